// Round 10
// baseline (202.270 us; speedup 1.0000x reference)
//
#include <hip/hip_runtime.h>
#include <hip/hip_bf16.h>
#include <math.h>

// Problem constants (fixed by the reference)
#define B_SZ   4096
#define D      64
#define RPB    8192                 // rows per branch = 2*B
#define NCHUNK 8                    // column chunks (blockIdx.y)
#define TPC    8                    // 128-col tiles per chunk
#define NPART  16                   // partials per row = NCHUNK * 2 (wn halves)
#define LN2    0.69314718055994531f
#define PRESCALE 2.6857914f         // sqrt(5 * log2(e)); X pre-scaled so Gram = base-2 logits
#define DEFER_THR 60.0f             // item max-defer threshold (terms <= 2^60, f32-safe)

typedef __attribute__((ext_vector_type(8))) short  bf16x8;
typedef __attribute__((ext_vector_type(4))) float  f32x4;

__device__ __forceinline__ float fexp2(float x) { return __builtin_amdgcn_exp2f(x); }

// Direct global->LDS copy, 16 B per lane, zero VGPR destination cost.
typedef const __attribute__((address_space(1))) unsigned int* gptr_t;
typedef __attribute__((address_space(3))) unsigned int* lptr_t;
__device__ __forceinline__ void stage16(const void* g, void* l) {
    __builtin_amdgcn_global_load_lds((gptr_t)g, (lptr_t)l, 16, 0, 0);
}

// ws layout:
//   Xbf  : 2*8192*64 bf16  = 2 MB   (pre-scaled by PRESCALE)
//   dots : 8192 float      = 32 KB  (v1_i . v2_i, unscaled fp32)
//   P    : 16384*16 float2 = 2 MB   (per-row per-(chunk,wn) (m,s), base-2; user m=0)

// ---------------------------------------------------------------------------
// Gather + normalize + dots + bf16 pack. Also zeroes the output scalar
// (stream-ordered before merge_kernel's atomics) -> no memset dispatch.
__global__ __launch_bounds__(256) void gather_kernel(
    const int* __restrict__ u_idx, const int* __restrict__ i_idx,
    const float* __restrict__ u1e, const float* __restrict__ i1e,
    const float* __restrict__ u2e, const float* __restrict__ i2e,
    __hip_bfloat16* __restrict__ Xbf, float* __restrict__ dots,
    float* __restrict__ out)
{
    const int tid  = threadIdx.x;
    if (blockIdx.x == 0 && tid == 0) *out = 0.f;
    const int wave = tid >> 6, lane = tid & 63;
    const int g      = blockIdx.x * 4 + wave;   // 0..8191
    const int branch = g >> 12;
    const int i      = g & (B_SZ - 1);
    const int idx    = (branch == 0) ? u_idx[i] : i_idx[i];
    const float* s1  = (branch == 0) ? u1e : i1e;
    const float* s2  = (branch == 0) ? u2e : i2e;

    float v1 = s1[(size_t)idx * D + lane];
    float v2 = s2[(size_t)idx * D + lane];
    if (branch == 0) {
        float a = v1 * v1, b = v2 * v2;
        #pragma unroll
        for (int o = 32; o > 0; o >>= 1) {
            a += __shfl_xor(a, o, 64);
            b += __shfl_xor(b, o, 64);
        }
        v1 *= rsqrtf(a);
        v2 *= rsqrtf(b);
    }
    float p = v1 * v2;
    #pragma unroll
    for (int o = 32; o > 0; o >>= 1) p += __shfl_xor(p, o, 64);
    if (lane == 0) dots[g] = p;

    const size_t row1 = (size_t)branch * RPB + i;
    Xbf[row1 * D + lane]          = __float2bfloat16(v1 * PRESCALE);
    Xbf[(row1 + B_SZ) * D + lane] = __float2bfloat16(v2 * PRESCALE);
}

// ---------------------------------------------------------------------------
// MFMA Gram + per-lane online logsumexp (base-2). R6-proven structure:
// B panels double-buffered 2x16KB via global_load_lds (zero VGPR cost);
// stage for tile t+1 issues at tile t's start; the compiler-inserted vmcnt
// drain before the end-of-tile barrier lands AFTER the exp2 epilogue.
// XOR swizzle (byte ^= (row&7)<<4) on the GLOBAL SOURCE address (LDS dest
// linear); ds_read applies the same XOR.
// R10: PER-NT tile body -- compute one nt's 4 MFMA accs (16 regs), fold into
// m/s immediately, reuse. Accumulator liveness 64 -> 16 regs cuts per-wave
// total ~148 -> ~112 in the unified 512-reg file => 4 blocks/CU resident
// (R2/R6 were register-limited to 3). 1024 blocks = 4*256: zero tail.
// Item branch: per-element deferred max (THR=60). m_run init 0.0f (finite:
// avoids -inf - -inf = NaN on the diag element); terms <= 2^60, per-lane
// s <= 32*2^60 = 2^65 << f32 max. Validated numerics in R9 (passed).
template<int IS_USER>
__device__ __forceinline__ void gram_body(
    const __hip_bfloat16* __restrict__ Xb, float2* __restrict__ P,
    const int bx, char* sm)
{
    const int tid   = threadIdx.x;
    const int chunk = blockIdx.y;
    const int r0    = bx * 128;
    const int wave = tid >> 6, lane = tid & 63;
    const int wm = wave >> 1, wn = wave & 1;
    const int quad = lane >> 4, tx = lane & 15;

    // Stage addressing: dest LDS byte L = wave*4096 + k*1024 + lane*16 (linear).
    // Source swizzle-adjusted: row = L>>7, srccol = (L&127) ^ ((row&7)<<4).
    const int srow_b = wave * 32 + (lane >> 3);                  // + k*8
    const int scb    = ((lane & 7) * 16) ^ ((lane >> 3) << 4);
    const char* Xbytes = (const char*)Xb;

    // Prologue: stage tile 0 of this chunk into buffer 0.
    {
        const char* src = Xbytes + (size_t)(chunk * TPC) * 16384;
        #pragma unroll
        for (int k = 0; k < 4; ++k)
            stage16(src + (srow_b + k * 8) * 128 + scb,
                    sm + wave * 4096 + k * 1024);
    }

    // A fragments hoisted to registers, straight from global (K=64 fits).
    bf16x8 afr[4][2];
    const __hip_bfloat16* Ap = Xb + (size_t)(r0 + wm * 64 + tx) * D + quad * 8;
    #pragma unroll
    for (int mt = 0; mt < 4; ++mt)
        #pragma unroll
        for (int ks = 0; ks < 2; ++ks)
            afr[mt][ks] = *(const bf16x8*)(Ap + mt * 16 * D + ks * 32);

    float m_run[16], s_run[16];
    #pragma unroll
    for (int r = 0; r < 16; ++r) { m_run[r] = 0.f; s_run[r] = 0.f; }

    const int lrq  = wm * 64 + quad * 4;   // + mt*16 + rr = block-local row
    const int lcol = wn * 64 + tx;         // + nt*16      = block-local col

    // ds_read addressing (swizzled): row = wn*64 + nt*16 + tx, row&7 = tx&7.
    const int rbase = (wn * 64 + tx) * 128;          // + nt*2048
    const int key   = (tx & 7) << 4;
    const int cb0   = (quad * 16) ^ key;
    const int cb1   = (64 + quad * 16) ^ key;

    __syncthreads();   // tile 0 staged (compiler drains vmcnt before barrier)

    #pragma unroll 1
    for (int t = 0; t < TPC; ++t) {
        const int ct  = chunk * TPC + t;
        const int cur = (t & 1) << 14;

        // Stage tile t+1 into the other buffer (WAR-safe across the barrier).
        if (t + 1 < TPC) {
            const char* src = Xbytes + (size_t)(ct + 1) * 16384;
            char* dst = sm + (((t + 1) & 1) << 14) + wave * 4096;
            #pragma unroll
            for (int k = 0; k < 4; ++k)
                stage16(src + (srow_b + k * 8) * 128 + scb, dst + k * 1024);
        }

        const bool diag = (ct == bx);
        const f32x4 z = {0.f, 0.f, 0.f, 0.f};

        // Per-nt: 2 ds_reads -> 8 MFMAs into 16-reg acc -> fold into m/s.
        #pragma unroll
        for (int nt = 0; nt < 4; ++nt) {
            const bf16x8 b0 = *(const bf16x8*)(sm + cur + rbase + nt * 2048 + cb0);
            const bf16x8 b1 = *(const bf16x8*)(sm + cur + rbase + nt * 2048 + cb1);
            f32x4 acc[4];
            #pragma unroll
            for (int mt = 0; mt < 4; ++mt)
                acc[mt] = __builtin_amdgcn_mfma_f32_16x16x32_bf16(afr[mt][0], b0, z, 0, 0, 0);
            #pragma unroll
            for (int mt = 0; mt < 4; ++mt)
                acc[mt] = __builtin_amdgcn_mfma_f32_16x16x32_bf16(afr[mt][1], b1, acc[mt], 0, 0, 0);

            #pragma unroll
            for (int mt = 0; mt < 4; ++mt) {
                #pragma unroll
                for (int rr = 0; rr < 4; ++rr) {
                    float y = acc[mt][rr];
                    if (diag && (lrq + mt * 16 + rr - lcol == nt * 16))
                        y = -INFINITY;                 // base-2 logits (pre-scaled X)
                    const int r = mt * 4 + rr;
                    if (IS_USER) {
                        s_run[r] += fexp2(y);
                    } else {
                        // Deferred max: rescale only when y jumps past m+THR.
                        if (__builtin_expect(y > m_run[r] + DEFER_THR, 0)) {
                            s_run[r] *= fexp2(m_run[r] - y);
                            m_run[r] = y;
                        }
                        s_run[r] += fexp2(y - m_run[r]);   // y=-inf -> +0 (m finite)
                    }
                }
            }
        }

        // End-of-tile barrier: drains this wave's stage loads and aligns
        // the buffer phases of the 4 waves.
        __syncthreads();
    }

    // Once per chunk: merge across the 16 tx lanes of THIS wave, write the
    // (row, chunk, wn) partial to its own slot. (m is a finite reference,
    // not necessarily the max -- the online merge below and merge_kernel
    // only require lse = m + log2(s), which holds for any finite m.)
    #pragma unroll
    for (int r = 0; r < 16; ++r) {
        float m = IS_USER ? 0.f : m_run[r];
        float s = s_run[r];
        #pragma unroll
        for (int o = 1; o < 16; o <<= 1) {
            if (IS_USER) {
                s += __shfl_xor(s, o, 64);
            } else {
                float om = __shfl_xor(m, o, 64);
                float os = __shfl_xor(s, o, 64);
                float M  = fmaxf(m, om);
                s = s * fexp2(m - M) + os * fexp2(om - M);
                m = M;
            }
        }
        if (tx == 0) {
            const int grow = r0 + wm * 64 + (r >> 2) * 16 + quad * 4 + (r & 3);
            P[(size_t)grow * NPART + chunk * 2 + wn] = make_float2(m, s);
        }
    }
}

__global__ __launch_bounds__(256, 2) void gram_lse_fused(
    const __hip_bfloat16* __restrict__ Xb0, float2* __restrict__ P0)
{
    __shared__ __align__(16) char sm[32768];     // 2 x 16KB B-panel buffers
    const int branch = blockIdx.x & 1;           // interleaved for CU balance
    const int bx     = blockIdx.x >> 1;
    const __hip_bfloat16* Xb = Xb0 + (size_t)branch * RPB * D;
    float2* P = P0 + (size_t)branch * RPB * NPART;
    if (branch == 0) gram_body<1>(Xb, P, bx, sm);
    else             gram_body<0>(Xb, P, bx, sm);
}

// ---------------------------------------------------------------------------
// Merge the 16 per-row partials -> lse -> reduce; fold in the positive-pair
// correction from dots[]. 128 blocks x 8-deep grid-stride.
__global__ __launch_bounds__(256) void merge_kernel(
    const float2* __restrict__ P, const float* __restrict__ dots,
    float* __restrict__ out)
{
    __shared__ float red[4];
    const int tid  = threadIdx.x;
    const int wave = tid >> 6, lane = tid & 63;

    float vsum = 0.f;
    #pragma unroll
    for (int k = 0; k < 8; ++k) {
        const int vb  = blockIdx.x * 8 + k;        // 0..1023
        const int gw  = vb * 4 + wave;             // 0..4095
        const int row = gw * 4 + (lane >> 4);      // 0..16383
        const int c   = lane & 15;

        float2 p = P[(size_t)row * NPART + c];
        float m = p.x, s = p.y;
        #pragma unroll
        for (int o = 1; o < 16; o <<= 1) {         // online merge across 16 lanes
            float om = __shfl_xor(m, o, 64);
            float os = __shfl_xor(s, o, 64);
            float M  = fmaxf(m, om);
            s = s * fexp2(m - M) + os * fexp2(om - M);
            m = M;
        }

        if ((lane & 15) == 0)
            vsum += LN2 * (m + log2f(s)) * (1.0f / (float)RPB);   // lse_row / (2B)
        if (tid < 8)                                              // positive-pair correction
            vsum -= dots[vb * 8 + tid] * (5.0f / (float)B_SZ);
    }

    float v = vsum;
    #pragma unroll
    for (int o = 32; o > 0; o >>= 1) v += __shfl_xor(v, o, 64);
    if (lane == 0) red[wave] = v;
    __syncthreads();
    if (tid == 0)
        atomicAdd(out, red[0] + red[1] + red[2] + red[3]);
}

// ---------------------------------------------------------------------------
extern "C" void kernel_launch(void* const* d_in, const int* in_sizes, int n_in,
                              void* d_out, int out_size, void* d_ws, size_t ws_size,
                              hipStream_t stream) {
    const int*   u_idx = (const int*)d_in[0];
    const int*   i_idx = (const int*)d_in[1];
    const float* u1e   = (const float*)d_in[2];
    const float* i1e   = (const float*)d_in[3];
    const float* u2e   = (const float*)d_in[4];
    const float* i2e   = (const float*)d_in[5];
    float* out = (float*)d_out;

    __hip_bfloat16* Xbf = (__hip_bfloat16*)d_ws;                  // 2 MB
    float*  dots = (float*)((char*)d_ws + 2 * RPB * D * 2);       // 32 KB
    float2* P    = (float2*)((char*)dots + RPB * sizeof(float));  // 2 MB

    gather_kernel<<<dim3(2048), dim3(256), 0, stream>>>(
        u_idx, i_idx, u1e, i1e, u2e, i2e, Xbf, dots, out);
    // both branches in one launch, interleaved on blockIdx.x parity
    gram_lse_fused<<<dim3(128, NCHUNK), dim3(256), 0, stream>>>(Xbf, P);
    merge_kernel<<<dim3(128), dim3(256), 0, stream>>>(P, dots, out);
}

// Round 11
// 185.169 us; speedup vs baseline: 1.0924x; 1.0924x over previous
//
#include <hip/hip_runtime.h>
#include <hip/hip_bf16.h>
#include <math.h>

// Problem constants (fixed by the reference)
#define B_SZ   4096
#define D      64
#define RPB    8192                 // rows per branch = 2*B
#define NCHUNK 16                   // column chunks (blockIdx.y)
#define TPC    4                    // 128-col tiles per chunk
#define NPART  32                   // partials per row = NCHUNK * 2 (wn halves)
#define LN2    0.69314718055994531f
#define PRESCALE 2.6857914f         // sqrt(5 * log2(e)); X pre-scaled so Gram = base-2 logits
#define DEFER_THR 60.0f             // item max-defer threshold (terms <= 2^60, f32-safe)

typedef __attribute__((ext_vector_type(8))) short  bf16x8;
typedef __attribute__((ext_vector_type(4))) float  f32x4;

__device__ __forceinline__ float fexp2(float x) { return __builtin_amdgcn_exp2f(x); }

// Direct global->LDS copy, 16 B per lane, zero VGPR destination cost.
typedef const __attribute__((address_space(1))) unsigned int* gptr_t;
typedef __attribute__((address_space(3))) unsigned int* lptr_t;
__device__ __forceinline__ void stage16(const void* g, void* l) {
    __builtin_amdgcn_global_load_lds((gptr_t)g, (lptr_t)l, 16, 0, 0);
}

// ws layout:
//   Xbf  : 2*8192*64 bf16  = 2 MB   (pre-scaled by PRESCALE)
//   dots : 8192 float      = 32 KB  (v1_i . v2_i, unscaled fp32)
//   P    : 16384*32 float2 = 4 MB   (per-row per-(chunk,wn) (m,s), base-2; user m=0)

// ---------------------------------------------------------------------------
// Gather + normalize + dots + bf16 pack. Also zeroes the output scalar
// (stream-ordered before merge_kernel's atomics).
__global__ __launch_bounds__(256) void gather_kernel(
    const int* __restrict__ u_idx, const int* __restrict__ i_idx,
    const float* __restrict__ u1e, const float* __restrict__ i1e,
    const float* __restrict__ u2e, const float* __restrict__ i2e,
    __hip_bfloat16* __restrict__ Xbf, float* __restrict__ dots,
    float* __restrict__ out)
{
    const int tid  = threadIdx.x;
    if (blockIdx.x == 0 && tid == 0) *out = 0.f;
    const int wave = tid >> 6, lane = tid & 63;
    const int g      = blockIdx.x * 4 + wave;   // 0..8191
    const int branch = g >> 12;
    const int i      = g & (B_SZ - 1);
    const int idx    = (branch == 0) ? u_idx[i] : i_idx[i];
    const float* s1  = (branch == 0) ? u1e : i1e;
    const float* s2  = (branch == 0) ? u2e : i2e;

    float v1 = s1[(size_t)idx * D + lane];
    float v2 = s2[(size_t)idx * D + lane];
    if (branch == 0) {
        float a = v1 * v1, b = v2 * v2;
        #pragma unroll
        for (int o = 32; o > 0; o >>= 1) {
            a += __shfl_xor(a, o, 64);
            b += __shfl_xor(b, o, 64);
        }
        v1 *= rsqrtf(a);
        v2 *= rsqrtf(b);
    }
    float p = v1 * v2;
    #pragma unroll
    for (int o = 32; o > 0; o >>= 1) p += __shfl_xor(p, o, 64);
    if (lane == 0) dots[g] = p;

    const size_t row1 = (size_t)branch * RPB + i;
    Xbf[row1 * D + lane]          = __float2bfloat16(v1 * PRESCALE);
    Xbf[(row1 + B_SZ) * D + lane] = __float2bfloat16(v2 * PRESCALE);
}

// ---------------------------------------------------------------------------
// MFMA Gram + per-lane online logsumexp (base-2). R6-proven pipeline:
// B panels double-buffered 2x16KB via global_load_lds (zero VGPR cost);
// stage for tile t+1 issues at tile t's start; compiler-inserted vmcnt drain
// before the end-of-tile barrier lands AFTER the exp2 epilogue.
// XOR swizzle (byte ^= (row&7)<<4) on the GLOBAL SOURCE address (LDS dest
// linear); ds_read applies the same XOR.
// R11: HALF-TILE accumulator -- per 64-col half: 4 ds_reads -> 16 MFMAs in
// 8 independent 2-deep chains -> epilogue fold. Acc liveness 64->32 AGPRs,
// b-frags 32->16 arch: per-wave total ~116 regs -> 4 waves/SIMD resident
// (R6 was 148 -> 3). R10's failure was 4-chain granularity + per-element
// branch; this keeps 8 chains and the R9-validated per-group deferred max.
// NCHUNK=16 (TPC=4): 2048 blocks = 8/CU queued at 4 resident, smooth tail.
// IS_USER=1: logits bounded (|y|<=7.3) -> plain exp2-sum.
template<int IS_USER>
__device__ __forceinline__ void gram_body(
    const __hip_bfloat16* __restrict__ Xb, float2* __restrict__ P,
    const int bx, char* sm)
{
    const int tid   = threadIdx.x;
    const int chunk = blockIdx.y;
    const int r0    = bx * 128;
    const int wave = tid >> 6, lane = tid & 63;
    const int wm = wave >> 1, wn = wave & 1;
    const int quad = lane >> 4, tx = lane & 15;

    // Stage addressing: dest LDS byte L = wave*4096 + k*1024 + lane*16 (linear).
    // Source swizzle-adjusted: row = L>>7, srccol = (L&127) ^ ((row&7)<<4).
    const int srow_b = wave * 32 + (lane >> 3);                  // + k*8
    const int scb    = ((lane & 7) * 16) ^ ((lane >> 3) << 4);
    const char* Xbytes = (const char*)Xb;

    // Prologue: stage tile 0 of this chunk into buffer 0.
    {
        const char* src = Xbytes + (size_t)(chunk * TPC) * 16384;
        #pragma unroll
        for (int k = 0; k < 4; ++k)
            stage16(src + (srow_b + k * 8) * 128 + scb,
                    sm + wave * 4096 + k * 1024);
    }

    // A fragments hoisted to registers, straight from global (K=64 fits).
    bf16x8 afr[4][2];
    const __hip_bfloat16* Ap = Xb + (size_t)(r0 + wm * 64 + tx) * D + quad * 8;
    #pragma unroll
    for (int mt = 0; mt < 4; ++mt)
        #pragma unroll
        for (int ks = 0; ks < 2; ++ks)
            afr[mt][ks] = *(const bf16x8*)(Ap + mt * 16 * D + ks * 32);

    float m_run[16], s_run[16];
    #pragma unroll
    for (int r = 0; r < 16; ++r) { m_run[r] = -INFINITY; s_run[r] = 0.f; }

    const int lrq  = wm * 64 + quad * 4;   // + mt*16 + rr = block-local row
    const int lcol = wn * 64 + tx;         // + nt*16      = block-local col

    // ds_read addressing (swizzled): row = wn*64 + nt*16 + tx, row&7 = tx&7.
    const int rbase = (wn * 64 + tx) * 128;          // + nt*2048
    const int key   = (tx & 7) << 4;
    const int cb0   = (quad * 16) ^ key;
    const int cb1   = (64 + quad * 16) ^ key;

    __syncthreads();   // tile 0 staged (compiler drains vmcnt before barrier)

    #pragma unroll 1
    for (int t = 0; t < TPC; ++t) {
        const int ct  = chunk * TPC + t;
        const int cur = (t & 1) << 14;

        // Stage tile t+1 into the other buffer (WAR-safe across the barrier).
        if (t + 1 < TPC) {
            const char* src = Xbytes + (size_t)(ct + 1) * 16384;
            char* dst = sm + (((t + 1) & 1) << 14) + wave * 4096;
            #pragma unroll
            for (int k = 0; k < 4; ++k)
                stage16(src + (srow_b + k * 8) * 128 + scb, dst + k * 1024);
        }

        const bool diag = (ct == bx);
        const f32x4 z = {0.f, 0.f, 0.f, 0.f};

        // Two 64-col halves: per half, 4 ds_reads -> 16 MFMAs (8 chains)
        // -> fold into m/s. Acc liveness 32 regs.
        #pragma unroll
        for (int h = 0; h < 2; ++h) {
            const int ntA = 2 * h, ntB = 2 * h + 1;
            const bf16x8 bA0 = *(const bf16x8*)(sm + cur + rbase + ntA * 2048 + cb0);
            const bf16x8 bA1 = *(const bf16x8*)(sm + cur + rbase + ntA * 2048 + cb1);
            const bf16x8 bB0 = *(const bf16x8*)(sm + cur + rbase + ntB * 2048 + cb0);
            const bf16x8 bB1 = *(const bf16x8*)(sm + cur + rbase + ntB * 2048 + cb1);

            f32x4 accA[4], accB[4];
            #pragma unroll
            for (int mt = 0; mt < 4; ++mt)
                accA[mt] = __builtin_amdgcn_mfma_f32_16x16x32_bf16(afr[mt][0], bA0, z, 0, 0, 0);
            #pragma unroll
            for (int mt = 0; mt < 4; ++mt)
                accB[mt] = __builtin_amdgcn_mfma_f32_16x16x32_bf16(afr[mt][0], bB0, z, 0, 0, 0);
            #pragma unroll
            for (int mt = 0; mt < 4; ++mt)
                accA[mt] = __builtin_amdgcn_mfma_f32_16x16x32_bf16(afr[mt][1], bA1, accA[mt], 0, 0, 0);
            #pragma unroll
            for (int mt = 0; mt < 4; ++mt)
                accB[mt] = __builtin_amdgcn_mfma_f32_16x16x32_bf16(afr[mt][1], bB1, accB[mt], 0, 0, 0);

            #pragma unroll
            for (int mt = 0; mt < 4; ++mt) {
                #pragma unroll
                for (int rr = 0; rr < 4; ++rr) {
                    float y0 = accA[mt][rr], y1 = accB[mt][rr];
                    if (diag) {              // acc already = base-2 logits
                        const int dr = lrq + mt * 16 + rr - lcol;
                        if (dr == h * 32)      y0 = -INFINITY;
                        if (dr == h * 32 + 16) y1 = -INFINITY;
                    }
                    const int r = mt * 4 + rr;
                    if (IS_USER) {
                        s_run[r] += fexp2(y0) + fexp2(y1);
                    } else {
                        // Deferred max (R9-validated): rescale only on jump >THR.
                        float mx = fmaxf(y0, y1);
                        if (__builtin_expect(mx > m_run[r] + DEFER_THR, 0)) {
                            s_run[r] *= fexp2(m_run[r] - mx);  // -inf first -> 0
                            m_run[r] = mx;
                        }
                        s_run[r] += fexp2(y0 - m_run[r]) + fexp2(y1 - m_run[r]);
                    }
                }
            }
        }

        // End-of-tile barrier: drains this wave's stage loads and aligns
        // the buffer phases of the 4 waves.
        __syncthreads();
    }

    // Once per chunk: merge across the 16 tx lanes of THIS wave, write the
    // (row, chunk, wn) partial to its own slot.
    #pragma unroll
    for (int r = 0; r < 16; ++r) {
        float m = IS_USER ? 0.f : m_run[r];
        float s = s_run[r];
        #pragma unroll
        for (int o = 1; o < 16; o <<= 1) {
            if (IS_USER) {
                s += __shfl_xor(s, o, 64);
            } else {
                float om = __shfl_xor(m, o, 64);
                float os = __shfl_xor(s, o, 64);
                float M  = fmaxf(m, om);
                s = s * fexp2(m - M) + os * fexp2(om - M);
                m = M;
            }
        }
        if (tx == 0) {
            const int grow = r0 + wm * 64 + (r >> 2) * 16 + quad * 4 + (r & 3);
            P[(size_t)grow * NPART + chunk * 2 + wn] = make_float2(m, s);
        }
    }
}

__global__ __launch_bounds__(256, 3) void gram_lse_fused(
    const __hip_bfloat16* __restrict__ Xb0, float2* __restrict__ P0)
{
    __shared__ __align__(16) char sm[32768];     // 2 x 16KB B-panel buffers
    const int branch = blockIdx.x & 1;           // interleaved for CU balance
    const int bx     = blockIdx.x >> 1;
    const __hip_bfloat16* Xb = Xb0 + (size_t)branch * RPB * D;
    float2* P = P0 + (size_t)branch * RPB * NPART;
    if (branch == 0) gram_body<1>(Xb, P, bx, sm);
    else             gram_body<0>(Xb, P, bx, sm);
}

// ---------------------------------------------------------------------------
// Merge the 32 per-row partials -> lse -> reduce; fold in the positive-pair
// correction from dots[]. 128 blocks; each covers 128 rows over 16 iters
// (each wave merges 2 rows with a 32-lane online merge). Passed R3-R5.
__global__ __launch_bounds__(256) void merge_kernel(
    const float2* __restrict__ P, const float* __restrict__ dots,
    float* __restrict__ out)
{
    __shared__ float red[4];
    const int tid  = threadIdx.x;
    const int wave = tid >> 6, lane = tid & 63;

    float vsum = 0.f;
    #pragma unroll
    for (int it = 0; it < 16; ++it) {
        const int row = blockIdx.x * 128 + it * 8 + wave * 2 + (lane >> 5);
        const int c   = lane & 31;

        float2 p = P[(size_t)row * NPART + c];
        float m = p.x, s = p.y;
        #pragma unroll
        for (int o = 1; o < 32; o <<= 1) {         // online merge across 32 lanes
            float om = __shfl_xor(m, o, 64);
            float os = __shfl_xor(s, o, 64);
            float M  = fmaxf(m, om);
            s = s * fexp2(m - M) + os * fexp2(om - M);
            m = M;
        }

        if ((lane & 31) == 0)
            vsum += LN2 * (m + log2f(s)) * (1.0f / (float)RPB);   // lse_row / (2B)
    }

    // positive-pair correction: 64 dots per block
    if (tid < 64)
        vsum -= dots[blockIdx.x * 64 + tid] * (5.0f / (float)B_SZ);

    float v = vsum;
    #pragma unroll
    for (int o = 32; o > 0; o >>= 1) v += __shfl_xor(v, o, 64);
    if (lane == 0) red[wave] = v;
    __syncthreads();
    if (tid == 0)
        atomicAdd(out, red[0] + red[1] + red[2] + red[3]);
}

// ---------------------------------------------------------------------------
extern "C" void kernel_launch(void* const* d_in, const int* in_sizes, int n_in,
                              void* d_out, int out_size, void* d_ws, size_t ws_size,
                              hipStream_t stream) {
    const int*   u_idx = (const int*)d_in[0];
    const int*   i_idx = (const int*)d_in[1];
    const float* u1e   = (const float*)d_in[2];
    const float* i1e   = (const float*)d_in[3];
    const float* u2e   = (const float*)d_in[4];
    const float* i2e   = (const float*)d_in[5];
    float* out = (float*)d_out;

    __hip_bfloat16* Xbf = (__hip_bfloat16*)d_ws;                  // 2 MB
    float*  dots = (float*)((char*)d_ws + 2 * RPB * D * 2);       // 32 KB
    float2* P    = (float2*)((char*)dots + RPB * sizeof(float));  // 4 MB

    gather_kernel<<<dim3(2048), dim3(256), 0, stream>>>(
        u_idx, i_idx, u1e, i1e, u2e, i2e, Xbf, dots, out);
    // both branches in one launch, interleaved on blockIdx.x parity
    gram_lse_fused<<<dim3(128, NCHUNK), dim3(256), 0, stream>>>(Xbf, P);
    merge_kernel<<<dim3(128), dim3(256), 0, stream>>>(P, dots, out);
}

// Round 12
// 171.473 us; speedup vs baseline: 1.1796x; 1.0799x over previous
//
#include <hip/hip_runtime.h>
#include <hip/hip_bf16.h>
#include <math.h>

// Problem constants (fixed by the reference)
#define B_SZ   4096
#define D      64
#define RPB    8192                 // rows per branch = 2*B
#define NCHUNK 6                    // column chunks (sizes 11,11,11,11,10,10 tiles)
#define NPART  16                   // P stride (12 slots used = NCHUNK*2)
#define LN2    0.69314718055994531f
#define PRESCALE 2.6857914f         // sqrt(5 * log2(e)); X pre-scaled so Gram = base-2 logits
#define DEFER_THR 60.0f             // item max-defer threshold (terms <= 2^60, f32-safe)

typedef __attribute__((ext_vector_type(8))) short  bf16x8;
typedef __attribute__((ext_vector_type(4))) float  f32x4;

__device__ __forceinline__ float fexp2(float x) { return __builtin_amdgcn_exp2f(x); }

// Direct global->LDS copy, 16 B per lane, zero VGPR destination cost.
typedef const __attribute__((address_space(1))) unsigned int* gptr_t;
typedef __attribute__((address_space(3))) unsigned int* lptr_t;
__device__ __forceinline__ void stage16(const void* g, void* l) {
    __builtin_amdgcn_global_load_lds((gptr_t)g, (lptr_t)l, 16, 0, 0);
}

// ws layout:
//   Xbf  : 2*8192*64 bf16  = 2 MB   (pre-scaled by PRESCALE)
//   dots : 8192 float      = 32 KB  (v1_i . v2_i, unscaled fp32)
//   P    : 16384*16 float2 = 2 MB   (per-row per-(chunk,wn) (m,s); slots 0..11 used)

// ---------------------------------------------------------------------------
// Gather + normalize + dots + bf16 pack. Also zeroes the output scalar
// (stream-ordered before merge_kernel's atomics).
__global__ __launch_bounds__(256) void gather_kernel(
    const int* __restrict__ u_idx, const int* __restrict__ i_idx,
    const float* __restrict__ u1e, const float* __restrict__ i1e,
    const float* __restrict__ u2e, const float* __restrict__ i2e,
    __hip_bfloat16* __restrict__ Xbf, float* __restrict__ dots,
    float* __restrict__ out)
{
    const int tid  = threadIdx.x;
    if (blockIdx.x == 0 && tid == 0) *out = 0.f;
    const int wave = tid >> 6, lane = tid & 63;
    const int g      = blockIdx.x * 4 + wave;   // 0..8191
    const int branch = g >> 12;
    const int i      = g & (B_SZ - 1);
    const int idx    = (branch == 0) ? u_idx[i] : i_idx[i];
    const float* s1  = (branch == 0) ? u1e : i1e;
    const float* s2  = (branch == 0) ? u2e : i2e;

    float v1 = s1[(size_t)idx * D + lane];
    float v2 = s2[(size_t)idx * D + lane];
    if (branch == 0) {
        float a = v1 * v1, b = v2 * v2;
        #pragma unroll
        for (int o = 32; o > 0; o >>= 1) {
            a += __shfl_xor(a, o, 64);
            b += __shfl_xor(b, o, 64);
        }
        v1 *= rsqrtf(a);
        v2 *= rsqrtf(b);
    }
    float p = v1 * v2;
    #pragma unroll
    for (int o = 32; o > 0; o >>= 1) p += __shfl_xor(p, o, 64);
    if (lane == 0) dots[g] = p;

    const size_t row1 = (size_t)branch * RPB + i;
    Xbf[row1 * D + lane]          = __float2bfloat16(v1 * PRESCALE);
    Xbf[(row1 + B_SZ) * D + lane] = __float2bfloat16(v2 * PRESCALE);
}

// ---------------------------------------------------------------------------
// MFMA Gram + per-lane online logsumexp (base-2). Inner loop BYTE-IDENTICAL
// to R6 (best measured: 32-MFMA bursts, 2x16KB global_load_lds double-buffer,
// XOR swizzle on global source + ds_read). R12 changes ONLY the grid:
// 768 blocks = 2 branches x 64 row-tiles x 6 chunks (11,11,11,11,10,10 tiles)
// = 3 blocks/CU ALL co-resident -> zero grid tail (R6's 1024 blocks ran as
// 768 + 256 stragglers at 1/3 utilization = ~33% of gram time wasted).
// Item branch: R9-proven deferred-max (THR=60, absmax 0 twice) to equalize
// per-tile cost with the user branch (kernel time = slowest resident block).
template<int IS_USER>
__device__ __forceinline__ void gram_body(
    const __hip_bfloat16* __restrict__ Xb, float2* __restrict__ P,
    const int bx, const int chunk, char* sm)
{
    const int tid  = threadIdx.x;
    const int r0   = bx * 128;
    const int wave = tid >> 6, lane = tid & 63;
    const int wm = wave >> 1, wn = wave & 1;
    const int quad = lane >> 4, tx = lane & 15;

    const int cstart = chunk * 11 - (chunk > 4 ? chunk - 4 : 0);  // 0,11,22,33,44,54
    const int ntile  = (chunk < 4) ? 11 : 10;

    // Stage addressing: dest LDS byte L = wave*4096 + k*1024 + lane*16 (linear).
    // Source swizzle-adjusted: row = L>>7, srccol = (L&127) ^ ((row&7)<<4).
    const int srow_b = wave * 32 + (lane >> 3);                  // + k*8
    const int scb    = ((lane & 7) * 16) ^ ((lane >> 3) << 4);
    const char* Xbytes = (const char*)Xb;

    // Prologue: stage first tile into buffer 0.
    {
        const char* src = Xbytes + (size_t)cstart * 16384;
        #pragma unroll
        for (int k = 0; k < 4; ++k)
            stage16(src + (srow_b + k * 8) * 128 + scb,
                    sm + wave * 4096 + k * 1024);
    }

    // A fragments hoisted to registers, straight from global (K=64 fits).
    bf16x8 afr[4][2];
    const __hip_bfloat16* Ap = Xb + (size_t)(r0 + wm * 64 + tx) * D + quad * 8;
    #pragma unroll
    for (int mt = 0; mt < 4; ++mt)
        #pragma unroll
        for (int ks = 0; ks < 2; ++ks)
            afr[mt][ks] = *(const bf16x8*)(Ap + mt * 16 * D + ks * 32);

    float m_run[16], s_run[16];
    #pragma unroll
    for (int r = 0; r < 16; ++r) { m_run[r] = -INFINITY; s_run[r] = 0.f; }

    const int lrq  = wm * 64 + quad * 4;   // + mt*16 + rr = block-local row
    const int lcol = wn * 64 + tx;         // + nt*16      = block-local col

    // ds_read addressing (swizzled): row = wn*64 + nt*16 + tx, row&7 = tx&7.
    const int rbase = (wn * 64 + tx) * 128;          // + nt*2048
    const int key   = (tx & 7) << 4;
    const int cb0   = (quad * 16) ^ key;
    const int cb1   = (64 + quad * 16) ^ key;

    __syncthreads();   // tile 0 staged (compiler drains vmcnt before barrier)

    #pragma unroll 1
    for (int t = 0; t < ntile; ++t) {
        const int ct  = cstart + t;
        const int cur = (t & 1) << 14;

        // Stage tile t+1 into the other buffer (WAR-safe across the barrier).
        if (t + 1 < ntile) {
            const char* src = Xbytes + (size_t)(ct + 1) * 16384;
            char* dst = sm + (((t + 1) & 1) << 14) + wave * 4096;
            #pragma unroll
            for (int k = 0; k < 4; ++k)
                stage16(src + (srow_b + k * 8) * 128 + scb, dst + k * 1024);
        }

        // B fragments from LDS (swizzled addresses).
        bf16x8 b0[4], b1[4];
        #pragma unroll
        for (int nt = 0; nt < 4; ++nt) {
            b0[nt] = *(const bf16x8*)(sm + cur + rbase + nt * 2048 + cb0);
            b1[nt] = *(const bf16x8*)(sm + cur + rbase + nt * 2048 + cb1);
        }

        f32x4 acc[4][4];
        const f32x4 z = {0.f, 0.f, 0.f, 0.f};
        #pragma unroll
        for (int nt = 0; nt < 4; ++nt)
            #pragma unroll
            for (int mt = 0; mt < 4; ++mt)
                acc[mt][nt] = __builtin_amdgcn_mfma_f32_16x16x32_bf16(afr[mt][0], b0[nt], z, 0, 0, 0);
        #pragma unroll
        for (int nt = 0; nt < 4; ++nt)
            #pragma unroll
            for (int mt = 0; mt < 4; ++mt)
                acc[mt][nt] = __builtin_amdgcn_mfma_f32_16x16x32_bf16(afr[mt][1], b1[nt], acc[mt][nt], 0, 0, 0);

        const bool diag = (ct == bx);
        #pragma unroll
        for (int mt = 0; mt < 4; ++mt) {
            #pragma unroll
            for (int rr = 0; rr < 4; ++rr) {
                float y0 = acc[mt][0][rr], y1 = acc[mt][1][rr],
                      y2 = acc[mt][2][rr], y3 = acc[mt][3][rr];
                if (diag) {                  // acc already = base-2 logits (pre-scaled X)
                    const int dr = lrq + mt * 16 + rr - lcol;
                    if (dr == 0)  y0 = -INFINITY;
                    if (dr == 16) y1 = -INFINITY;
                    if (dr == 32) y2 = -INFINITY;
                    if (dr == 48) y3 = -INFINITY;
                }
                const int r = mt * 4 + rr;
                if (IS_USER) {
                    s_run[r] += fexp2(y0) + fexp2(y1) + fexp2(y2) + fexp2(y3);
                } else {
                    // Deferred max (R9-proven): rescale only on jump > THR.
                    float mx = fmaxf(fmaxf(y0, y1), fmaxf(y2, y3));
                    if (__builtin_expect(mx > m_run[r] + DEFER_THR, 0)) {
                        s_run[r] *= fexp2(m_run[r] - mx);   // -inf first -> s stays 0
                        m_run[r] = mx;
                    }
                    const float m = m_run[r];
                    s_run[r] += fexp2(y0 - m) + fexp2(y1 - m)
                              + fexp2(y2 - m) + fexp2(y3 - m);
                }
            }
        }

        // End-of-tile barrier: drains this wave's stage loads and aligns
        // the buffer phases of the 4 waves.
        __syncthreads();
    }

    // Once per chunk: merge across the 16 tx lanes of THIS wave, write the
    // (row, chunk, wn) partial to its own slot. (For item, m is a finite
    // reference after the first tile; lse = m + log2(s) invariant holds.)
    #pragma unroll
    for (int r = 0; r < 16; ++r) {
        float m = IS_USER ? 0.f : m_run[r];
        float s = s_run[r];
        #pragma unroll
        for (int o = 1; o < 16; o <<= 1) {
            if (IS_USER) {
                s += __shfl_xor(s, o, 64);
            } else {
                float om = __shfl_xor(m, o, 64);
                float os = __shfl_xor(s, o, 64);
                float M  = fmaxf(m, om);
                s = s * fexp2(m - M) + os * fexp2(om - M);
                m = M;
            }
        }
        if (tx == 0) {
            const int grow = r0 + wm * 64 + (r >> 2) * 16 + quad * 4 + (r & 3);
            P[(size_t)grow * NPART + chunk * 2 + wn] = make_float2(m, s);
        }
    }
}

__global__ __launch_bounds__(256, 3) void gram_lse_fused(
    const __hip_bfloat16* __restrict__ Xb0, float2* __restrict__ P0)
{
    __shared__ __align__(16) char sm[32768];     // 2 x 16KB B-panel buffers
    const int bid    = blockIdx.x;               // 0..767
    const int branch = bid & 1;                  // interleaved for CU balance
    const int rest   = bid >> 1;                 // 0..383
    const int bx     = rest & 63;                // row tile
    const int chunk  = rest >> 6;                // 0..5
    const __hip_bfloat16* Xb = Xb0 + (size_t)branch * RPB * D;
    float2* P = P0 + (size_t)branch * RPB * NPART;
    if (branch == 0) gram_body<1>(Xb, P, bx, chunk, sm);
    else             gram_body<0>(Xb, P, bx, chunk, sm);
}

// ---------------------------------------------------------------------------
// Merge the 12 per-row partials (stride-16 slots, c<12 valid) -> lse ->
// reduce; fold in the positive-pair correction. 128 blocks x 8-deep stride.
// Neutral (m=0, s=0) for c>=12: contributes s*2^(0-M)=0, no NaN paths.
__global__ __launch_bounds__(256) void merge_kernel(
    const float2* __restrict__ P, const float* __restrict__ dots,
    float* __restrict__ out)
{
    __shared__ float red[4];
    const int tid  = threadIdx.x;
    const int wave = tid >> 6, lane = tid & 63;

    float vsum = 0.f;
    #pragma unroll
    for (int k = 0; k < 8; ++k) {
        const int vb  = blockIdx.x * 8 + k;        // 0..1023
        const int gw  = vb * 4 + wave;             // 0..4095
        const int row = gw * 4 + (lane >> 4);      // 0..16383
        const int c   = lane & 15;

        float2 p = (c < 12) ? P[(size_t)row * NPART + c] : make_float2(0.f, 0.f);
        float m = p.x, s = p.y;
        #pragma unroll
        for (int o = 1; o < 16; o <<= 1) {         // online merge across 16 lanes
            float om = __shfl_xor(m, o, 64);
            float os = __shfl_xor(s, o, 64);
            float M  = fmaxf(m, om);
            s = s * fexp2(m - M) + os * fexp2(om - M);
            m = M;
        }

        if ((lane & 15) == 0)
            vsum += LN2 * (m + log2f(s)) * (1.0f / (float)RPB);   // lse_row / (2B)
        if (tid < 8)                                              // positive-pair correction
            vsum -= dots[vb * 8 + tid] * (5.0f / (float)B_SZ);
    }

    float v = vsum;
    #pragma unroll
    for (int o = 32; o > 0; o >>= 1) v += __shfl_xor(v, o, 64);
    if (lane == 0) red[wave] = v;
    __syncthreads();
    if (tid == 0)
        atomicAdd(out, red[0] + red[1] + red[2] + red[3]);
}

// ---------------------------------------------------------------------------
extern "C" void kernel_launch(void* const* d_in, const int* in_sizes, int n_in,
                              void* d_out, int out_size, void* d_ws, size_t ws_size,
                              hipStream_t stream) {
    const int*   u_idx = (const int*)d_in[0];
    const int*   i_idx = (const int*)d_in[1];
    const float* u1e   = (const float*)d_in[2];
    const float* i1e   = (const float*)d_in[3];
    const float* u2e   = (const float*)d_in[4];
    const float* i2e   = (const float*)d_in[5];
    float* out = (float*)d_out;

    __hip_bfloat16* Xbf = (__hip_bfloat16*)d_ws;                  // 2 MB
    float*  dots = (float*)((char*)d_ws + 2 * RPB * D * 2);       // 32 KB
    float2* P    = (float2*)((char*)dots + RPB * sizeof(float));  // 2 MB

    gather_kernel<<<dim3(2048), dim3(256), 0, stream>>>(
        u_idx, i_idx, u1e, i1e, u2e, i2e, Xbf, dots, out);
    // 768 blocks = 3/CU, all co-resident, zero tail
    gram_lse_fused<<<dim3(768), dim3(256), 0, stream>>>(Xbf, P);
    merge_kernel<<<dim3(128), dim3(256), 0, stream>>>(P, dots, out);
}